// Round 1
// baseline (312.737 us; speedup 1.0000x reference)
//
#include <hip/hip_runtime.h>
#include <cmath>

#define NTOK 1728
#define DIMC 128
#define NHEAD 8
#define HD 16
#define NB 4
#define TABN (12167 * 8)

// ---------------- K0: expT = exp(rel_pos_table), 97336 elems ----------------
__global__ __launch_bounds__(256) void k_exp_table(const float* __restrict__ tbl,
                                                   float* __restrict__ expT) {
    int i = blockIdx.x * 256 + threadIdx.x;
    if (i < TABN) expT[i] = expf(tbl[i]);
}

// ---------------- K1: q/k/v projections (blockIdx.y selects matrix) ---------
// grid (108, 3), block 256. Per WG: 64 rows of x (B*N flattened) x 128 cols.
__global__ __launch_bounds__(256) void k_proj_qkv(
    const float* __restrict__ x, const float* __restrict__ Wq,
    const float* __restrict__ Wk, const float* __restrict__ Wv,
    float* __restrict__ QS, float* __restrict__ Ko, float* __restrict__ Vo)
{
    __shared__ float xs[64][132];   // +4 pad keeps 16B alignment, breaks bank aliasing
    const int m = blockIdx.y;
    const int t = threadIdx.x;
    const int row0 = blockIdx.x * 64;
    const float* __restrict__ W = (m == 0) ? Wq : ((m == 1) ? Wk : Wv);

    for (int r = t; r < 64 * 32; r += 256) {
        int rr = r >> 5, cc = (r & 31) << 2;
        *reinterpret_cast<float4*>(&xs[rr][cc]) =
            *reinterpret_cast<const float4*>(&x[(size_t)(row0 + rr) * DIMC + cc]);
    }
    __syncthreads();

    const int nl = t & 63, g = t >> 6;     // lane = row, wave = 32-channel group
    const int ch0 = g * 32;
    float acc[32];
    #pragma unroll
    for (int i = 0; i < 32; ++i) acc[i] = 0.f;

    for (int c4 = 0; c4 < 32; ++c4) {
        const float4 xv = *reinterpret_cast<const float4*>(&xs[nl][c4 << 2]);
        #pragma unroll
        for (int cc = 0; cc < 32; ++cc) {
            // wave-uniform address -> scalar/broadcast load from L1/L2
            const float4 wv = *reinterpret_cast<const float4*>(
                &W[(size_t)(ch0 + cc) * DIMC + (c4 << 2)]);
            acc[cc] = fmaf(xv.x, wv.x, fmaf(xv.y, wv.y,
                      fmaf(xv.z, wv.z, fmaf(xv.w, wv.w, acc[cc]))));
        }
    }

    float* __restrict__ Out = (m == 0) ? QS : ((m == 1) ? Ko : Vo);
    const size_t ob = (size_t)(row0 + nl) * DIMC + ch0;
    if (m == 0) {
        #pragma unroll
        for (int cc = 0; cc < 32; ++cc) acc[cc] = 1.f / (1.f + expf(-acc[cc]));
    }
    #pragma unroll
    for (int cc = 0; cc < 32; cc += 4) {
        float4 v; v.x = acc[cc]; v.y = acc[cc + 1]; v.z = acc[cc + 2]; v.w = acc[cc + 3];
        *reinterpret_cast<float4*>(&Out[ob + cc]) = v;
    }
}

// ---------------- K1b: EKV[h][j][b][0..15]=exp(k)*v, [16..31]=exp(k) --------
// grid (27, 8), block 256: thread = (b = t&3, jj = t>>2)
__global__ __launch_bounds__(256) void k_build_ekv(
    const float* __restrict__ Ko, const float* __restrict__ Vo,
    float* __restrict__ EKV)
{
    const int t = threadIdx.x;
    const int h = blockIdx.y;
    const int j = blockIdx.x * 64 + (t >> 2);
    const int b = t & 3;
    const float* kp = &Ko[((size_t)b * NTOK + j) * DIMC + h * HD];
    const float* vp = &Vo[((size_t)b * NTOK + j) * DIMC + h * HD];
    float kv[16], vv[16];
    #pragma unroll
    for (int d4 = 0; d4 < 4; ++d4) {
        *reinterpret_cast<float4*>(&kv[d4 * 4]) = *reinterpret_cast<const float4*>(&kp[d4 * 4]);
        *reinterpret_cast<float4*>(&vv[d4 * 4]) = *reinterpret_cast<const float4*>(&vp[d4 * 4]);
    }
    float ob[32];
    #pragma unroll
    for (int d = 0; d < 16; ++d) {
        float e = expf(kv[d]);           // kmax subtraction cancels in num/den
        ob[d] = e * vv[d];
        ob[16 + d] = e;
    }
    float* op = &EKV[(((size_t)h * NTOK + j) * NB + b) * 32];
    #pragma unroll
    for (int c = 0; c < 32; c += 4)
        *reinterpret_cast<float4*>(&op[c]) = *reinterpret_cast<const float4*>(&ob[c]);
}

// ---------------- K2: main einsum  part[js][h][i][b][32] --------------------
// grid (27, 8, 3), block 256 = 4 waves (wave = batch b).
// Lane l: il = l&15 (i mod 16), chq = l>>4 (8-channel quarter). TM = 4 i's.
__global__ __launch_bounds__(256) void k_aft_main(
    const int* __restrict__ ridx, const float* __restrict__ expT,
    const float* __restrict__ EKV, float* __restrict__ part)
{
    __shared__ float wlds[64][65];      // w[j][i], 65 stride -> conflict-free both phases
    __shared__ float elds[64][128];     // ekv[j][b*32+ch]
    const int t = threadIdx.x;
    const int i0 = blockIdx.x * 64;
    const int h  = blockIdx.y;
    const int js = blockIdx.z;

    const int l = t & 63, b = t >> 6;
    const int il = l & 15, chq = l >> 4;
    const int co = chq * 8;

    float acc[4][8];
    #pragma unroll
    for (int m = 0; m < 4; ++m)
        #pragma unroll
        for (int c = 0; c < 8; ++c) acc[m][c] = 0.f;

    for (int jt = 0; jt < 9; ++jt) {
        const int j0 = (js * 9 + jt) * 64;
        __syncthreads();
        // stage ekv tile (contiguous 32KB, fully coalesced)
        {
            const float4* src = reinterpret_cast<const float4*>(
                &EKV[((size_t)h * NTOK + j0) * (NB * 32)]);
            float4* dst = reinterpret_cast<float4*>(&elds[0][0]);
            #pragma unroll
            for (int r = 0; r < 8; ++r) dst[t + r * 256] = src[t + r * 256];
        }
        // gather w tile: lane = j (coalesced rel_index), expT gather is L1/L2-local
        {
            const int* ip = &ridx[(size_t)(i0 + b * 16) * NTOK + j0 + l];
            #pragma unroll
            for (int r = 0; r < 16; ++r) {
                int idx = ip[(size_t)r * NTOK];
                wlds[l][b * 16 + r] = expT[idx * NHEAD + h];
            }
        }
        __syncthreads();
        #pragma unroll 4
        for (int j = 0; j < 64; ++j) {
            float ev[8];
            *reinterpret_cast<float4*>(&ev[0]) =
                *reinterpret_cast<const float4*>(&elds[j][b * 32 + co]);
            *reinterpret_cast<float4*>(&ev[4]) =
                *reinterpret_cast<const float4*>(&elds[j][b * 32 + co + 4]);
            #pragma unroll
            for (int m = 0; m < 4; ++m) {
                const float w = wlds[j][il + 16 * m];
                #pragma unroll
                for (int c = 0; c < 8; ++c) acc[m][c] = fmaf(w, ev[c], acc[m][c]);
            }
        }
    }
    #pragma unroll
    for (int m = 0; m < 4; ++m) {
        const int i = i0 + il + 16 * m;
        float* op = &part[(((size_t)js * NHEAD + h) * NTOK + i) * (NB * 32) + b * 32 + co];
        float4 v0; v0.x = acc[m][0]; v0.y = acc[m][1]; v0.z = acc[m][2]; v0.w = acc[m][3];
        float4 v1; v1.x = acc[m][4]; v1.y = acc[m][5]; v1.z = acc[m][6]; v1.w = acc[m][7];
        *reinterpret_cast<float4*>(&op[0]) = v0;
        *reinterpret_cast<float4*>(&op[4]) = v1;
    }
}

// ---------------- K3: reduce partials, y = sigmoid(q) * num/den -------------
// 55296 threads: gid -> (h, b, i), 16 d's each
__global__ __launch_bounds__(256) void k_reduce_y(
    const float* __restrict__ part, const float* __restrict__ QS,
    float* __restrict__ Y)
{
    const int gid = blockIdx.x * 256 + threadIdx.x;
    const int h = gid / (NB * NTOK);
    const int bi = gid - h * (NB * NTOK);
    const int b = bi / NTOK;
    const int i = bi - b * NTOK;
    float num[16], den[16];
    #pragma unroll
    for (int d = 0; d < 16; ++d) { num[d] = 0.f; den[d] = 0.f; }
    #pragma unroll
    for (int js = 0; js < 3; ++js) {
        const float* pp = &part[(((size_t)js * NHEAD + h) * NTOK + i) * (NB * 32) + b * 32];
        #pragma unroll
        for (int c4 = 0; c4 < 4; ++c4) {
            float4 n4 = *reinterpret_cast<const float4*>(&pp[c4 * 4]);
            float4 d4 = *reinterpret_cast<const float4*>(&pp[16 + c4 * 4]);
            num[c4*4+0] += n4.x; num[c4*4+1] += n4.y; num[c4*4+2] += n4.z; num[c4*4+3] += n4.w;
            den[c4*4+0] += d4.x; den[c4*4+1] += d4.y; den[c4*4+2] += d4.z; den[c4*4+3] += d4.w;
        }
    }
    const size_t yb = ((size_t)b * NTOK + i) * DIMC + h * HD;
    #pragma unroll
    for (int d4 = 0; d4 < 4; ++d4) {
        float4 q4 = *reinterpret_cast<const float4*>(&QS[yb + d4 * 4]);
        float4 o;
        o.x = q4.x * num[d4*4+0] / den[d4*4+0];
        o.y = q4.y * num[d4*4+1] / den[d4*4+1];
        o.z = q4.z * num[d4*4+2] / den[d4*4+2];
        o.w = q4.w * num[d4*4+3] / den[d4*4+3];
        *reinterpret_cast<float4*>(&Y[yb + d4 * 4]) = o;
    }
}

// ---------------- K4: out = Y @ Wp^T + bp -----------------------------------
__global__ __launch_bounds__(256) void k_proj_out(
    const float* __restrict__ Y, const float* __restrict__ Wp,
    const float* __restrict__ bp, float* __restrict__ out)
{
    __shared__ float ys[64][132];
    const int t = threadIdx.x;
    const int row0 = blockIdx.x * 64;
    for (int r = t; r < 64 * 32; r += 256) {
        int rr = r >> 5, cc = (r & 31) << 2;
        *reinterpret_cast<float4*>(&ys[rr][cc]) =
            *reinterpret_cast<const float4*>(&Y[(size_t)(row0 + rr) * DIMC + cc]);
    }
    __syncthreads();
    const int nl = t & 63, g = t >> 6;
    const int ch0 = g * 32;
    float acc[32];
    #pragma unroll
    for (int i = 0; i < 32; ++i) acc[i] = 0.f;
    for (int c4 = 0; c4 < 32; ++c4) {
        const float4 xv = *reinterpret_cast<const float4*>(&ys[nl][c4 << 2]);
        #pragma unroll
        for (int cc = 0; cc < 32; ++cc) {
            const float4 wv = *reinterpret_cast<const float4*>(
                &Wp[(size_t)(ch0 + cc) * DIMC + (c4 << 2)]);
            acc[cc] = fmaf(xv.x, wv.x, fmaf(xv.y, wv.y,
                      fmaf(xv.z, wv.z, fmaf(xv.w, wv.w, acc[cc]))));
        }
    }
    const size_t ob = (size_t)(row0 + nl) * DIMC + ch0;
    #pragma unroll
    for (int cc = 0; cc < 32; cc += 4) {
        float4 v;
        v.x = acc[cc]     + bp[ch0 + cc];
        v.y = acc[cc + 1] + bp[ch0 + cc + 1];
        v.z = acc[cc + 2] + bp[ch0 + cc + 2];
        v.w = acc[cc + 3] + bp[ch0 + cc + 3];
        *reinterpret_cast<float4*>(&out[ob + cc]) = v;
    }
}

extern "C" void kernel_launch(void* const* d_in, const int* in_sizes, int n_in,
                              void* d_out, int out_size, void* d_ws, size_t ws_size,
                              hipStream_t stream) {
    const float* x    = (const float*)d_in[0];
    const float* Wq   = (const float*)d_in[1];
    const float* Wk   = (const float*)d_in[2];
    const float* Wv   = (const float*)d_in[3];
    const float* Wp   = (const float*)d_in[4];
    const float* bp   = (const float*)d_in[5];
    const float* tbl  = (const float*)d_in[6];
    const int*   ridx = (const int*)d_in[7];
    float* out = (float*)d_out;

    float* ws = (float*)d_ws;
    const size_t szQ = (size_t)NB * NTOK * DIMC;          // 884736
    float* expT = ws;                                     // 97336 (pad to 97344)
    float* QS   = expT + 97344;
    float* Ko   = QS + szQ;
    float* Vo   = Ko + szQ;
    float* EKV  = Vo + szQ;                               // 8*1728*4*32 = 1769472
    float* part = EKV + (size_t)NHEAD * NTOK * NB * 32;   // 3 * 1769472
    float* Yb   = part + 3 * (size_t)NHEAD * NTOK * NB * 32;

    k_exp_table<<<dim3((TABN + 255) / 256), 256, 0, stream>>>(tbl, expT);
    k_proj_qkv<<<dim3((NB * NTOK) / 64, 3), 256, 0, stream>>>(x, Wq, Wk, Wv, QS, Ko, Vo);
    k_build_ekv<<<dim3(NTOK / 64, NHEAD), 256, 0, stream>>>(Ko, Vo, EKV);
    k_aft_main<<<dim3(NTOK / 64, NHEAD, 3), 256, 0, stream>>>(ridx, expT, EKV, part);
    k_reduce_y<<<dim3((NB * NTOK * NHEAD) / 256), 256, 0, stream>>>(part, QS, Yb);
    k_proj_out<<<dim3((NB * NTOK) / 64), 256, 0, stream>>>(Yb, Wp, bp, out);
}

// Round 2
// 221.580 us; speedup vs baseline: 1.4114x; 1.4114x over previous
//
#include <hip/hip_runtime.h>
#include <hip/hip_bf16.h>
#include <cmath>

#define NTOK 1728
#define DIMC 128
#define NHEAD 8
#define NB 4
#define TABN (12167 * 8)

typedef __attribute__((ext_vector_type(8))) short bf16x8;
typedef __attribute__((ext_vector_type(4))) float f32x4;

static __device__ __forceinline__ unsigned short f2bf(float f) {
    union { float f; unsigned u; } v; v.f = f;
    unsigned r = v.u + 0x7fff + ((v.u >> 16) & 1);   // RNE
    return (unsigned short)(r >> 16);
}

// ---- K0: ridx -> u16, tblm1 = bf16(expm1(table)) ---------------------------
__global__ __launch_bounds__(256) void k_prep(
    const int* __restrict__ ridx, const float* __restrict__ tbl,
    unsigned short* __restrict__ ridx16, unsigned short* __restrict__ tblm1)
{
    const int bid = blockIdx.x, t = threadIdx.x;
    if (bid < 2916) {
        const int g4 = (bid * 256 + t) * 4;
        int4 v = *reinterpret_cast<const int4*>(&ridx[g4]);
        ushort4 o;
        o.x = (unsigned short)v.x; o.y = (unsigned short)v.y;
        o.z = (unsigned short)v.z; o.w = (unsigned short)v.w;
        *reinterpret_cast<ushort4*>(&ridx16[g4]) = o;
    } else {
        const int g4 = ((bid - 2916) * 256 + t) * 4;
        #pragma unroll
        for (int e = 0; e < 4; ++e) {
            const int g = g4 + e;
            if (g < TABN) tblm1[g] = f2bf(expm1f(tbl[g]));
        }
    }
}

// ---- K1: q/k/v projections. block: 64 rows x 32 cols, W staged in LDS ------
__global__ __launch_bounds__(256) void k_proj_qkv(
    const float* __restrict__ x, const float* __restrict__ Wq,
    const float* __restrict__ Wk, const float* __restrict__ Wv,
    float* __restrict__ QS, float* __restrict__ Ko, float* __restrict__ Vo)
{
    __shared__ __align__(16) float xs[64 * 128];
    __shared__ __align__(16) float Ws[32 * 128];
    const int t = threadIdx.x;
    const int row0 = blockIdx.x * 64;
    const int cg = blockIdx.y;           // 32-col group
    const int m = blockIdx.z;            // matrix select
    const float* __restrict__ W = (m == 0) ? Wq : (m == 1) ? Wk : Wv;

    {   // stage x tile, XOR-swizzled in 16B units
        const int cc = t & 31;
        #pragma unroll
        for (int p = 0; p < 8; ++p) {
            const int r = (t >> 5) + p * 8;
            float4 v = *reinterpret_cast<const float4*>(&x[(size_t)(row0 + r) * DIMC + cc * 4]);
            *reinterpret_cast<float4*>(&xs[r * 128 + ((cc * 4) ^ ((r & 7) << 2))]) = v;
        }
    }
    {   // stage W slice [32 cols][128 k], linear (read via broadcast)
        const int cc = t & 31;
        #pragma unroll
        for (int p = 0; p < 4; ++p) {
            const int c = (t >> 5) + p * 8;
            float4 v = *reinterpret_cast<const float4*>(&W[(size_t)(cg * 32 + c) * DIMC + cc * 4]);
            *reinterpret_cast<float4*>(&Ws[c * 128 + cc * 4]) = v;
        }
    }
    __syncthreads();
    const int nl = t & 63, w = t >> 6;
    float acc[8];
    #pragma unroll
    for (int c = 0; c < 8; ++c) acc[c] = 0.f;
    for (int k4 = 0; k4 < 32; ++k4) {
        const float4 xv = *reinterpret_cast<const float4*>(
            &xs[nl * 128 + ((k4 * 4) ^ ((nl & 7) << 2))]);
        #pragma unroll
        for (int c = 0; c < 8; ++c) {
            const float4 wv = *reinterpret_cast<const float4*>(&Ws[(w * 8 + c) * 128 + k4 * 4]);
            acc[c] = fmaf(xv.x, wv.x, fmaf(xv.y, wv.y,
                     fmaf(xv.z, wv.z, fmaf(xv.w, wv.w, acc[c]))));
        }
    }
    if (m == 0) {
        #pragma unroll
        for (int c = 0; c < 8; ++c) acc[c] = 1.f / (1.f + expf(-acc[c]));
    }
    __syncthreads();
    float* res = Ws;                      // reuse as 64x33 bounce buffer
    #pragma unroll
    for (int c = 0; c < 8; ++c) res[nl * 33 + w * 8 + c] = acc[c];
    __syncthreads();
    float* __restrict__ Out = (m == 0) ? QS : (m == 1) ? Ko : Vo;
    {
        const int r = t >> 2, q = t & 3;
        float4 v0, v1;
        v0.x = res[r*33 + q*8 + 0]; v0.y = res[r*33 + q*8 + 1];
        v0.z = res[r*33 + q*8 + 2]; v0.w = res[r*33 + q*8 + 3];
        v1.x = res[r*33 + q*8 + 4]; v1.y = res[r*33 + q*8 + 5];
        v1.z = res[r*33 + q*8 + 6]; v1.w = res[r*33 + q*8 + 7];
        *reinterpret_cast<float4*>(&Out[(size_t)(row0 + r) * DIMC + cg * 32 + q * 8]) = v0;
        *reinterpret_cast<float4*>(&Out[(size_t)(row0 + r) * DIMC + cg * 32 + q * 8 + 4]) = v1;
    }
}

// ---- K2: EKV fp32 [h][j][b][32] + EKVt bf16 [h][b*32+c][j] -----------------
__global__ __launch_bounds__(256) void k_build_ekv(
    const float* __restrict__ Ko, const float* __restrict__ Vo,
    float* __restrict__ EKV, unsigned short* __restrict__ EKVt)
{
    const int t = threadIdx.x;
    const int h = blockIdx.y;
    const int jj = t >> 2, b = t & 3;
    const int j = blockIdx.x * 64 + jj;
    const float* kp = &Ko[((size_t)b * NTOK + j) * DIMC + h * 16];
    const float* vp = &Vo[((size_t)b * NTOK + j) * DIMC + h * 16];
    float kv[16], vv[16], ob[32];
    #pragma unroll
    for (int d4 = 0; d4 < 4; ++d4) {
        *reinterpret_cast<float4*>(&kv[d4 * 4]) = *reinterpret_cast<const float4*>(&kp[d4 * 4]);
        *reinterpret_cast<float4*>(&vv[d4 * 4]) = *reinterpret_cast<const float4*>(&vp[d4 * 4]);
    }
    #pragma unroll
    for (int d = 0; d < 16; ++d) {
        float e = expf(kv[d]);            // kmax/bmax cancel in num/den
        ob[d] = e * vv[d];
        ob[16 + d] = e;
    }
    float* op = &EKV[(((size_t)h * NTOK + j) * NB + b) * 32];
    #pragma unroll
    for (int c = 0; c < 32; c += 4)
        *reinterpret_cast<float4*>(&op[c]) = *reinterpret_cast<const float4*>(&ob[c]);
    #pragma unroll
    for (int c = 0; c < 32; ++c)
        EKVt[((size_t)h * DIMC + b * 32 + c) * NTOK + j] = f2bf(ob[c]);
}

// ---- K3: n1[h][b][32] = sum_j EKV (exact fp32 "1" part of w = 1 + w') ------
__global__ __launch_bounds__(256) void k_colsum(const float* __restrict__ EKV,
                                                float* __restrict__ n1)
{
    __shared__ float red[256][32];
    const int t = threadIdx.x;
    const int h = blockIdx.x, b = blockIdx.y;
    float acc[32];
    #pragma unroll
    for (int c = 0; c < 32; ++c) acc[c] = 0.f;
    for (int j = t; j < NTOK; j += 256) {
        const float* p = &EKV[(((size_t)h * NTOK + j) * NB + b) * 32];
        #pragma unroll
        for (int c4 = 0; c4 < 8; ++c4) {
            float4 v = *reinterpret_cast<const float4*>(&p[c4 * 4]);
            acc[c4*4+0] += v.x; acc[c4*4+1] += v.y;
            acc[c4*4+2] += v.z; acc[c4*4+3] += v.w;
        }
    }
    #pragma unroll
    for (int c = 0; c < 32; ++c) red[t][c] = acc[c];
    __syncthreads();
    if (t < 32) {
        float s = 0.f;
        for (int r = 0; r < 256; ++r) s += red[r][t];
        n1[(h * NB + b) * 32 + t] = s;
    }
}

// ---- K4: MFMA correction  part[js][h][i][c] = sum_j w'_ij * ekv[j][c] ------
__global__ __launch_bounds__(256) void k_aft_mfma(
    const unsigned short* __restrict__ ridx16,
    const unsigned short* __restrict__ tblm1,
    const unsigned short* __restrict__ EKVt,
    float* __restrict__ part)
{
    __shared__ __align__(16) unsigned short alds[64 * 64];   // w' tile, swizzled
    __shared__ __align__(16) unsigned short blds[128 * 64];  // ekv tile, swizzled
    const int t = threadIdx.x;
    const int i0 = blockIdx.x * 64;
    const int h = blockIdx.y;
    const int js = blockIdx.z;
    const int l = t & 63, w = t >> 6;
    const int il = l & 15, kg = l >> 4;

    f32x4 acc[8];
    #pragma unroll
    for (int cf = 0; cf < 8; ++cf) acc[cf] = (f32x4){0.f, 0.f, 0.f, 0.f};

    const int gj = t & 63;           // gather lane = j (coalesced ridx)
    const int gi0 = (t >> 6) * 16;   // 16 i-rows per thread
    const int bc = t >> 3;           // B-stage: c base
    const int bj8 = (t & 7) * 8;     // B-stage: j offset

    for (int jt = 0; jt < 9; ++jt) {
        const int j0 = (js * 9 + jt) * 64;
        __syncthreads();
        // stage B: EKVt[h][c][j0..j0+63] -> blds[c][j] (XOR-swizzled 16B units)
        #pragma unroll
        for (int p = 0; p < 4; ++p) {
            const int c = bc + p * 32;
            bf16x8 v = *reinterpret_cast<const bf16x8*>(
                &EKVt[((size_t)h * DIMC + c) * NTOK + j0 + bj8]);
            *reinterpret_cast<bf16x8*>(&blds[c * 64 + (bj8 ^ ((c & 7) << 3))]) = v;
        }
        // gather A: w'[i][j] = tblm1[ridx[i][j]*8 + h]
        {
            const unsigned short* ip = &ridx16[(size_t)(i0 + gi0) * NTOK + j0 + gj];
            #pragma unroll
            for (int r = 0; r < 16; ++r) {
                const int idx = ip[(size_t)r * NTOK];
                const int i = gi0 + r;
                alds[i * 64 + (gj ^ ((i & 7) << 3))] = tblm1[idx * 8 + h];
            }
        }
        __syncthreads();
        #pragma unroll
        for (int kk = 0; kk < 2; ++kk) {
            const int ia = w * 16 + il;
            const int ka = kk * 32 + kg * 8;
            bf16x8 af = *reinterpret_cast<const bf16x8*>(
                &alds[ia * 64 + (ka ^ ((ia & 7) << 3))]);
            #pragma unroll
            for (int cf = 0; cf < 8; ++cf) {
                const int cb = cf * 16 + il;
                bf16x8 bf = *reinterpret_cast<const bf16x8*>(
                    &blds[cb * 64 + (ka ^ ((cb & 7) << 3))]);
                acc[cf] = __builtin_amdgcn_mfma_f32_16x16x32_bf16(af, bf, acc[cf], 0, 0, 0);
            }
        }
    }
    #pragma unroll
    for (int cf = 0; cf < 8; ++cf) {
        #pragma unroll
        for (int r = 0; r < 4; ++r) {
            const int i = i0 + w * 16 + kg * 4 + r;   // D: row=(l>>4)*4+reg
            const int c = cf * 16 + il;               //    col=l&15
            part[(((size_t)js * NHEAD + h) * NTOK + i) * DIMC + c] = acc[cf][r];
        }
    }
}

// ---- K5: y = sigmoid(q) * (n1 + sum_js part_num) / (d1 + sum_js part_den) --
__global__ __launch_bounds__(256) void k_reduce_y(
    const float* __restrict__ part, const float* __restrict__ n1,
    const float* __restrict__ QS, float* __restrict__ Y)
{
    const int gid = blockIdx.x * 256 + threadIdx.x;   // 55296 = 8*4*1728
    const int h = gid / (NB * NTOK);
    const int bi = gid - h * (NB * NTOK);
    const int b = bi / NTOK;
    const int i = bi - b * NTOK;
    float nu[16], de[16];
    const float* np = &n1[(h * NB + b) * 32];
    #pragma unroll
    for (int d = 0; d < 16; ++d) { nu[d] = np[d]; de[d] = np[16 + d]; }
    #pragma unroll
    for (int js = 0; js < 3; ++js) {
        const float* pp = &part[(((size_t)js * NHEAD + h) * NTOK + i) * DIMC + b * 32];
        #pragma unroll
        for (int c4 = 0; c4 < 4; ++c4) {
            float4 a  = *reinterpret_cast<const float4*>(&pp[c4 * 4]);
            float4 d4 = *reinterpret_cast<const float4*>(&pp[16 + c4 * 4]);
            nu[c4*4+0] += a.x;  nu[c4*4+1] += a.y;  nu[c4*4+2] += a.z;  nu[c4*4+3] += a.w;
            de[c4*4+0] += d4.x; de[c4*4+1] += d4.y; de[c4*4+2] += d4.z; de[c4*4+3] += d4.w;
        }
    }
    const size_t yb = ((size_t)b * NTOK + i) * DIMC + h * 16;
    #pragma unroll
    for (int d4 = 0; d4 < 4; ++d4) {
        float4 q4 = *reinterpret_cast<const float4*>(&QS[yb + d4 * 4]);
        float4 o;
        o.x = q4.x * nu[d4*4+0] / de[d4*4+0];
        o.y = q4.y * nu[d4*4+1] / de[d4*4+1];
        o.z = q4.z * nu[d4*4+2] / de[d4*4+2];
        o.w = q4.w * nu[d4*4+3] / de[d4*4+3];
        *reinterpret_cast<float4*>(&Y[yb + d4 * 4]) = o;
    }
}

// ---- K6: out = Y @ Wp^T + bp ----------------------------------------------
__global__ __launch_bounds__(256) void k_proj_out(
    const float* __restrict__ Y, const float* __restrict__ Wp,
    const float* __restrict__ bp, float* __restrict__ out)
{
    __shared__ __align__(16) float xs[64 * 128];
    __shared__ __align__(16) float Ws[32 * 128];
    const int t = threadIdx.x;
    const int row0 = blockIdx.x * 64;
    const int cg = blockIdx.y;
    {
        const int cc = t & 31;
        #pragma unroll
        for (int p = 0; p < 8; ++p) {
            const int r = (t >> 5) + p * 8;
            float4 v = *reinterpret_cast<const float4*>(&Y[(size_t)(row0 + r) * DIMC + cc * 4]);
            *reinterpret_cast<float4*>(&xs[r * 128 + ((cc * 4) ^ ((r & 7) << 2))]) = v;
        }
    }
    {
        const int cc = t & 31;
        #pragma unroll
        for (int p = 0; p < 4; ++p) {
            const int c = (t >> 5) + p * 8;
            float4 v = *reinterpret_cast<const float4*>(&Wp[(size_t)(cg * 32 + c) * DIMC + cc * 4]);
            *reinterpret_cast<float4*>(&Ws[c * 128 + cc * 4]) = v;
        }
    }
    __syncthreads();
    const int nl = t & 63, w = t >> 6;
    float acc[8];
    #pragma unroll
    for (int c = 0; c < 8; ++c) acc[c] = 0.f;
    for (int k4 = 0; k4 < 32; ++k4) {
        const float4 xv = *reinterpret_cast<const float4*>(
            &xs[nl * 128 + ((k4 * 4) ^ ((nl & 7) << 2))]);
        #pragma unroll
        for (int c = 0; c < 8; ++c) {
            const float4 wv = *reinterpret_cast<const float4*>(&Ws[(w * 8 + c) * 128 + k4 * 4]);
            acc[c] = fmaf(xv.x, wv.x, fmaf(xv.y, wv.y,
                     fmaf(xv.z, wv.z, fmaf(xv.w, wv.w, acc[c]))));
        }
    }
    #pragma unroll
    for (int c = 0; c < 8; ++c) acc[c] += bp[cg * 32 + w * 8 + c];
    __syncthreads();
    float* res = Ws;
    #pragma unroll
    for (int c = 0; c < 8; ++c) res[nl * 33 + w * 8 + c] = acc[c];
    __syncthreads();
    {
        const int r = t >> 2, q = t & 3;
        float4 v0, v1;
        v0.x = res[r*33 + q*8 + 0]; v0.y = res[r*33 + q*8 + 1];
        v0.z = res[r*33 + q*8 + 2]; v0.w = res[r*33 + q*8 + 3];
        v1.x = res[r*33 + q*8 + 4]; v1.y = res[r*33 + q*8 + 5];
        v1.z = res[r*33 + q*8 + 6]; v1.w = res[r*33 + q*8 + 7];
        *reinterpret_cast<float4*>(&out[(size_t)(row0 + r) * DIMC + cg * 32 + q * 8]) = v0;
        *reinterpret_cast<float4*>(&out[(size_t)(row0 + r) * DIMC + cg * 32 + q * 8 + 4]) = v1;
    }
}

extern "C" void kernel_launch(void* const* d_in, const int* in_sizes, int n_in,
                              void* d_out, int out_size, void* d_ws, size_t ws_size,
                              hipStream_t stream) {
    const float* x    = (const float*)d_in[0];
    const float* Wq   = (const float*)d_in[1];
    const float* Wk   = (const float*)d_in[2];
    const float* Wv   = (const float*)d_in[3];
    const float* Wp   = (const float*)d_in[4];
    const float* bp   = (const float*)d_in[5];
    const float* tbl  = (const float*)d_in[6];
    const int*   ridx = (const int*)d_in[7];
    float* out = (float*)d_out;

    float* ws = (float*)d_ws;
    unsigned short* tblm1 = (unsigned short*)ws;                 // 97336 sh -> 48672 f32
    float* base1 = ws + 48672;
    unsigned short* ridx16 = (unsigned short*)base1;             // 2985984 sh = 1492992 f32
    float* QS  = base1 + 1492992;
    float* Ko  = QS + 884736;
    float* Vo  = Ko + 884736;
    float* EKV = Vo + 884736;                                    // 1769472 f32
    unsigned short* EKVt = (unsigned short*)(EKV + 1769472);     // 1769472 sh = 884736 f32
    float* n1   = EKV + 1769472 + 884736;                        // 1024 f32
    float* part = n1 + 1024;                                     // 5308416 f32
    float* Yb   = part + (size_t)3 * NHEAD * NTOK * DIMC;        // 884736 f32

    k_prep<<<dim3(3012), 256, 0, stream>>>(ridx, tbl, ridx16, tblm1);
    k_proj_qkv<<<dim3(108, 4, 3), 256, 0, stream>>>(x, Wq, Wk, Wv, QS, Ko, Vo);
    k_build_ekv<<<dim3(27, 8), 256, 0, stream>>>(Ko, Vo, EKV, EKVt);
    k_colsum<<<dim3(8, 4), 256, 0, stream>>>(EKV, n1);
    k_aft_mfma<<<dim3(27, 8, 3), 256, 0, stream>>>(ridx16, tblm1, EKVt, part);
    k_reduce_y<<<dim3(216), 256, 0, stream>>>(part, n1, QS, Yb);
    k_proj_out<<<dim3(108, 4), 256, 0, stream>>>(Yb, Wp, bp, out);
}

// Round 3
// 166.853 us; speedup vs baseline: 1.8743x; 1.3280x over previous
//
#include <hip/hip_runtime.h>
#include <hip/hip_bf16.h>
#include <cmath>

#define NTOK 1728
#define DIMC 128
#define NHEAD 8
#define NB 4
#define TABN (12167 * 8)

typedef __attribute__((ext_vector_type(8))) short bf16x8;
typedef __attribute__((ext_vector_type(4))) float f32x4;

static __device__ __forceinline__ unsigned short f2bf(float f) {
    union { float f; unsigned u; } v; v.f = f;
    unsigned r = v.u + 0x7fff + ((v.u >> 16) & 1);   // RNE
    return (unsigned short)(r >> 16);
}

// ---- K1: q/k/v projections (z<3); z==3: tblm1 = bf16(expm1(table)) ---------
__global__ __launch_bounds__(256) void k_proj_qkv(
    const float* __restrict__ x, const float* __restrict__ Wq,
    const float* __restrict__ Wk, const float* __restrict__ Wv,
    const float* __restrict__ tbl, unsigned short* __restrict__ tblm1,
    float* __restrict__ QS, float* __restrict__ Ko, float* __restrict__ Vo)
{
    __shared__ __align__(16) float xs[64 * 128];
    __shared__ __align__(16) float Ws[32 * 128];
    const int t = threadIdx.x;
    const int m = blockIdx.z;            // 0..2 matrix select, 3 = table prep
    if (m == 3) {
        const int g = (blockIdx.y * 108 + blockIdx.x) * 256 + t;
        if (g < TABN) tblm1[g] = f2bf(expm1f(tbl[g]));
        return;
    }
    const int row0 = blockIdx.x * 64;
    const int cg = blockIdx.y;           // 32-col group
    const float* __restrict__ W = (m == 0) ? Wq : (m == 1) ? Wk : Wv;

    {   // stage x tile, XOR-swizzled in 16B units
        const int cc = t & 31;
        #pragma unroll
        for (int p = 0; p < 8; ++p) {
            const int r = (t >> 5) + p * 8;
            float4 v = *reinterpret_cast<const float4*>(&x[(size_t)(row0 + r) * DIMC + cc * 4]);
            *reinterpret_cast<float4*>(&xs[r * 128 + ((cc * 4) ^ ((r & 7) << 2))]) = v;
        }
    }
    {   // stage W slice [32 cols][128 k], linear (read via broadcast)
        const int cc = t & 31;
        #pragma unroll
        for (int p = 0; p < 4; ++p) {
            const int c = (t >> 5) + p * 8;
            float4 v = *reinterpret_cast<const float4*>(&W[(size_t)(cg * 32 + c) * DIMC + cc * 4]);
            *reinterpret_cast<float4*>(&Ws[c * 128 + cc * 4]) = v;
        }
    }
    __syncthreads();
    const int nl = t & 63, w = t >> 6;
    float acc[8];
    #pragma unroll
    for (int c = 0; c < 8; ++c) acc[c] = 0.f;
    for (int k4 = 0; k4 < 32; ++k4) {
        const float4 xv = *reinterpret_cast<const float4*>(
            &xs[nl * 128 + ((k4 * 4) ^ ((nl & 7) << 2))]);
        #pragma unroll
        for (int c = 0; c < 8; ++c) {
            const float4 wv = *reinterpret_cast<const float4*>(&Ws[(w * 8 + c) * 128 + k4 * 4]);
            acc[c] = fmaf(xv.x, wv.x, fmaf(xv.y, wv.y,
                     fmaf(xv.z, wv.z, fmaf(xv.w, wv.w, acc[c]))));
        }
    }
    if (m == 0) {
        #pragma unroll
        for (int c = 0; c < 8; ++c) acc[c] = 1.f / (1.f + expf(-acc[c]));
    }
    __syncthreads();
    float* res = Ws;                      // reuse as 64x33 bounce buffer
    #pragma unroll
    for (int c = 0; c < 8; ++c) res[nl * 33 + w * 8 + c] = acc[c];
    __syncthreads();
    float* __restrict__ Out = (m == 0) ? QS : (m == 1) ? Ko : Vo;
    {
        const int r = t >> 2, q = t & 3;
        float4 v0, v1;
        v0.x = res[r*33 + q*8 + 0]; v0.y = res[r*33 + q*8 + 1];
        v0.z = res[r*33 + q*8 + 2]; v0.w = res[r*33 + q*8 + 3];
        v1.x = res[r*33 + q*8 + 4]; v1.y = res[r*33 + q*8 + 5];
        v1.z = res[r*33 + q*8 + 6]; v1.w = res[r*33 + q*8 + 7];
        *reinterpret_cast<float4*>(&Out[(size_t)(row0 + r) * DIMC + cg * 32 + q * 8]) = v0;
        *reinterpret_cast<float4*>(&Out[(size_t)(row0 + r) * DIMC + cg * 32 + q * 8 + 4]) = v1;
    }
}

// ---- K2: EKVt bf16 [h][b*32+c][j] + n1 partial colsums (atomicAdd) ---------
// grid (27, 8), block 256: wave = b, lane = jj (coalesced EKVt stores)
__global__ __launch_bounds__(256) void k_build_ekv(
    const float* __restrict__ Ko, const float* __restrict__ Vo,
    unsigned short* __restrict__ EKVt, float* __restrict__ n1)
{
    __shared__ float red[256][33];
    const int t = threadIdx.x;
    const int h = blockIdx.y;
    const int b = t >> 6, jj = t & 63;
    const int j = blockIdx.x * 64 + jj;
    const float* kp = &Ko[((size_t)b * NTOK + j) * DIMC + h * 16];
    const float* vp = &Vo[((size_t)b * NTOK + j) * DIMC + h * 16];
    float kv[16], vv[16], ob[32];
    #pragma unroll
    for (int d4 = 0; d4 < 4; ++d4) {
        *reinterpret_cast<float4*>(&kv[d4 * 4]) = *reinterpret_cast<const float4*>(&kp[d4 * 4]);
        *reinterpret_cast<float4*>(&vv[d4 * 4]) = *reinterpret_cast<const float4*>(&vp[d4 * 4]);
    }
    #pragma unroll
    for (int d = 0; d < 16; ++d) {
        float e = expf(kv[d]);            // kmax/bmax cancel in num/den
        ob[d] = e * vv[d];
        ob[16 + d] = e;
    }
    #pragma unroll
    for (int c = 0; c < 32; ++c)
        EKVt[((size_t)h * DIMC + b * 32 + c) * NTOK + j] = f2bf(ob[c]);
    #pragma unroll
    for (int c = 0; c < 32; ++c) red[t][c] = ob[c];
    __syncthreads();
    if (t < 128) {
        const int b2 = t >> 5, c = t & 31;
        float s = 0.f;
        for (int r = 0; r < 64; ++r) s += red[b2 * 64 + r][c];
        atomicAdd(&n1[(h * NB + b2) * 32 + c], s);
    }
}

// ---- K3: MFMA correction  part[js][h][i][c] = sum_j w'_ij * ekv[j][c] ------
// w'[i][j] = tblm1[P(i) - P(j) + 6083], P(t) = (t/144)*529 + ((t/12)%12)*23 + t%12
__global__ __launch_bounds__(256) void k_aft_mfma(
    const unsigned short* __restrict__ tblm1,
    const unsigned short* __restrict__ EKVt,
    float* __restrict__ part)
{
    __shared__ __align__(16) unsigned short alds[64 * 64];   // w' tile, swizzled
    __shared__ __align__(16) unsigned short blds[128 * 64];  // ekv tile, swizzled
    const int t = threadIdx.x;
    const int i0 = blockIdx.x * 64;
    const int h = blockIdx.y;
    const int js = blockIdx.z;
    const int l = t & 63, w = t >> 6;
    const int il = l & 15, kg = l >> 4;

    // gather setup: thread covers 16 i-rows (w*16..+15), lane column gj = l
    const int gj = l;
    const int gi0 = w * 16;
    unsigned qb[16];
    #pragma unroll
    for (int r = 0; r < 16; ++r) {
        const int i = i0 + gi0 + r;
        const int hi = i / 144, wi = (i / 12) % 12, di = i % 12;
        qb[r] = (unsigned)((hi * 529 + wi * 23 + di + 6083) * 8 + h);
    }
    const int bc = t >> 3;           // B-stage: c base
    const int bj8 = (t & 7) * 8;     // B-stage: j offset

    f32x4 acc[8];
    #pragma unroll
    for (int cf = 0; cf < 8; ++cf) acc[cf] = (f32x4){0.f, 0.f, 0.f, 0.f};

    for (int jt = 0; jt < 9; ++jt) {
        const int j0 = (js * 9 + jt) * 64;
        const int j = j0 + gj;
        const int hj = j / 144, wj = (j / 12) % 12, dj = j % 12;
        const unsigned pj8 = (unsigned)((hj * 529 + wj * 23 + dj) * 8);
        __syncthreads();
        // stage B: EKVt[h][c][j0..j0+63] -> blds[c][j] (XOR-swizzled 16B units)
        #pragma unroll
        for (int p = 0; p < 4; ++p) {
            const int c = bc + p * 32;
            bf16x8 v = *reinterpret_cast<const bf16x8*>(
                &EKVt[((size_t)h * DIMC + c) * NTOK + j0 + bj8]);
            *reinterpret_cast<bf16x8*>(&blds[c * 64 + (bj8 ^ ((c & 7) << 3))]) = v;
        }
        // stage A: arithmetic-index gather from L1-resident table
        #pragma unroll
        for (int r = 0; r < 16; ++r) {
            const unsigned short wv = tblm1[qb[r] - pj8];
            alds[(gi0 + r) * 64 + (gj ^ ((r & 7) << 3))] = wv;
        }
        __syncthreads();
        #pragma unroll
        for (int kk = 0; kk < 2; ++kk) {
            const int ia = w * 16 + il;
            const int ka = kk * 32 + kg * 8;
            bf16x8 af = *reinterpret_cast<const bf16x8*>(
                &alds[ia * 64 + (ka ^ ((ia & 7) << 3))]);
            #pragma unroll
            for (int cf = 0; cf < 8; ++cf) {
                const int cb = cf * 16 + il;
                bf16x8 bf = *reinterpret_cast<const bf16x8*>(
                    &blds[cb * 64 + (ka ^ ((cb & 7) << 3))]);
                acc[cf] = __builtin_amdgcn_mfma_f32_16x16x32_bf16(af, bf, acc[cf], 0, 0, 0);
            }
        }
    }
    #pragma unroll
    for (int cf = 0; cf < 8; ++cf) {
        #pragma unroll
        for (int r = 0; r < 4; ++r) {
            const int i = i0 + w * 16 + kg * 4 + r;   // D: row=(l>>4)*4+reg
            const int c = cf * 16 + il;               //    col=l&15
            part[(((size_t)js * NHEAD + h) * NTOK + i) * DIMC + c] = acc[cf][r];
        }
    }
}

// ---- K4: y = sigmoid(q) * (n1 + sum_js part_num) / (n1d + sum_js part_den) -
__global__ __launch_bounds__(256) void k_reduce_y(
    const float* __restrict__ part, const float* __restrict__ n1,
    const float* __restrict__ QS, float* __restrict__ Y)
{
    const int gid = blockIdx.x * 256 + threadIdx.x;   // 55296 = 8*4*1728
    const int h = gid / (NB * NTOK);
    const int bi = gid - h * (NB * NTOK);
    const int b = bi / NTOK;
    const int i = bi - b * NTOK;
    float nu[16], de[16];
    const float* np = &n1[(h * NB + b) * 32];
    #pragma unroll
    for (int d = 0; d < 16; ++d) { nu[d] = np[d]; de[d] = np[16 + d]; }
    #pragma unroll
    for (int js = 0; js < 3; ++js) {
        const float* pp = &part[(((size_t)js * NHEAD + h) * NTOK + i) * DIMC + b * 32];
        #pragma unroll
        for (int c4 = 0; c4 < 4; ++c4) {
            float4 a  = *reinterpret_cast<const float4*>(&pp[c4 * 4]);
            float4 d4 = *reinterpret_cast<const float4*>(&pp[16 + c4 * 4]);
            nu[c4*4+0] += a.x;  nu[c4*4+1] += a.y;  nu[c4*4+2] += a.z;  nu[c4*4+3] += a.w;
            de[c4*4+0] += d4.x; de[c4*4+1] += d4.y; de[c4*4+2] += d4.z; de[c4*4+3] += d4.w;
        }
    }
    const size_t yb = ((size_t)b * NTOK + i) * DIMC + h * 16;
    #pragma unroll
    for (int d4 = 0; d4 < 4; ++d4) {
        float4 q4 = *reinterpret_cast<const float4*>(&QS[yb + d4 * 4]);
        float4 o;
        o.x = q4.x * nu[d4*4+0] / de[d4*4+0];
        o.y = q4.y * nu[d4*4+1] / de[d4*4+1];
        o.z = q4.z * nu[d4*4+2] / de[d4*4+2];
        o.w = q4.w * nu[d4*4+3] / de[d4*4+3];
        *reinterpret_cast<float4*>(&Y[yb + d4 * 4]) = o;
    }
}

// ---- K5: out = Y @ Wp^T + bp ----------------------------------------------
__global__ __launch_bounds__(256) void k_proj_out(
    const float* __restrict__ Y, const float* __restrict__ Wp,
    const float* __restrict__ bp, float* __restrict__ out)
{
    __shared__ __align__(16) float xs[64 * 128];
    __shared__ __align__(16) float Ws[32 * 128];
    const int t = threadIdx.x;
    const int row0 = blockIdx.x * 64;
    const int cg = blockIdx.y;
    {
        const int cc = t & 31;
        #pragma unroll
        for (int p = 0; p < 8; ++p) {
            const int r = (t >> 5) + p * 8;
            float4 v = *reinterpret_cast<const float4*>(&Y[(size_t)(row0 + r) * DIMC + cc * 4]);
            *reinterpret_cast<float4*>(&xs[r * 128 + ((cc * 4) ^ ((r & 7) << 2))]) = v;
        }
    }
    {
        const int cc = t & 31;
        #pragma unroll
        for (int p = 0; p < 4; ++p) {
            const int c = (t >> 5) + p * 8;
            float4 v = *reinterpret_cast<const float4*>(&Wp[(size_t)(cg * 32 + c) * DIMC + cc * 4]);
            *reinterpret_cast<float4*>(&Ws[c * 128 + cc * 4]) = v;
        }
    }
    __syncthreads();
    const int nl = t & 63, w = t >> 6;
    float acc[8];
    #pragma unroll
    for (int c = 0; c < 8; ++c) acc[c] = 0.f;
    for (int k4 = 0; k4 < 32; ++k4) {
        const float4 xv = *reinterpret_cast<const float4*>(
            &xs[nl * 128 + ((k4 * 4) ^ ((nl & 7) << 2))]);
        #pragma unroll
        for (int c = 0; c < 8; ++c) {
            const float4 wv = *reinterpret_cast<const float4*>(&Ws[(w * 8 + c) * 128 + k4 * 4]);
            acc[c] = fmaf(xv.x, wv.x, fmaf(xv.y, wv.y,
                     fmaf(xv.z, wv.z, fmaf(xv.w, wv.w, acc[c]))));
        }
    }
    #pragma unroll
    for (int c = 0; c < 8; ++c) acc[c] += bp[cg * 32 + w * 8 + c];
    __syncthreads();
    float* res = Ws;
    #pragma unroll
    for (int c = 0; c < 8; ++c) res[nl * 33 + w * 8 + c] = acc[c];
    __syncthreads();
    {
        const int r = t >> 2, q = t & 3;
        float4 v0, v1;
        v0.x = res[r*33 + q*8 + 0]; v0.y = res[r*33 + q*8 + 1];
        v0.z = res[r*33 + q*8 + 2]; v0.w = res[r*33 + q*8 + 3];
        v1.x = res[r*33 + q*8 + 4]; v1.y = res[r*33 + q*8 + 5];
        v1.z = res[r*33 + q*8 + 6]; v1.w = res[r*33 + q*8 + 7];
        *reinterpret_cast<float4*>(&out[(size_t)(row0 + r) * DIMC + cg * 32 + q * 8]) = v0;
        *reinterpret_cast<float4*>(&out[(size_t)(row0 + r) * DIMC + cg * 32 + q * 8 + 4]) = v1;
    }
}

extern "C" void kernel_launch(void* const* d_in, const int* in_sizes, int n_in,
                              void* d_out, int out_size, void* d_ws, size_t ws_size,
                              hipStream_t stream) {
    const float* x    = (const float*)d_in[0];
    const float* Wq   = (const float*)d_in[1];
    const float* Wk   = (const float*)d_in[2];
    const float* Wv   = (const float*)d_in[3];
    const float* Wp   = (const float*)d_in[4];
    const float* bp   = (const float*)d_in[5];
    const float* tbl  = (const float*)d_in[6];
    float* out = (float*)d_out;

    float* ws = (float*)d_ws;
    unsigned short* tblm1 = (unsigned short*)ws;                 // 97344 sh = 48672 f32
    float* QS  = ws + 48672;
    float* Ko  = QS + 884736;
    float* Vo  = Ko + 884736;
    unsigned short* EKVt = (unsigned short*)(Vo + 884736);       // 1769472 sh = 884736 f32
    float* n1   = Vo + 884736 + 884736;                          // 1024 f32
    float* part = n1 + 1024;                                     // 5308416 f32
    float* Yb   = part + (size_t)3 * NHEAD * NTOK * DIMC;        // 884736 f32

    hipMemsetAsync(n1, 0, 1024 * sizeof(float), stream);
    k_proj_qkv<<<dim3(108, 4, 4), 256, 0, stream>>>(x, Wq, Wk, Wv, tbl, tblm1, QS, Ko, Vo);
    k_build_ekv<<<dim3(27, 8), 256, 0, stream>>>(Ko, Vo, EKVt, n1);
    k_aft_mfma<<<dim3(27, 8, 3), 256, 0, stream>>>(tblm1, EKVt, part);
    k_reduce_y<<<dim3(216), 256, 0, stream>>>(part, n1, QS, Yb);
    k_proj_out<<<dim3(108, 4), 256, 0, stream>>>(Yb, Wp, bp, out);
}

// Round 4
// 146.924 us; speedup vs baseline: 2.1286x; 1.1356x over previous
//
#include <hip/hip_runtime.h>
#include <hip/hip_bf16.h>
#include <cmath>

#define NTOK 1728
#define DIMC 128
#define NHEAD 8
#define NB 4
#define TABN 12167
#define TSTRIDE 12168   // u16 row stride for tblT[h][idx]

typedef __attribute__((ext_vector_type(8))) short bf16x8;
typedef __attribute__((ext_vector_type(4))) float f32x4;

static __device__ __forceinline__ unsigned short f2bf(float f) {
    union { float f; unsigned u; } v; v.f = f;
    unsigned r = v.u + 0x7fff + ((v.u >> 16) & 1);   // RNE
    return (unsigned short)(r >> 16);
}

static __device__ __forceinline__ int Pdec(int t) {
    return (t / 144) * 529 + ((t / 12) % 12) * 23 + (t % 12);
}

// ---- K1: q/k/v projections (z<3); z==3: tblT[h][idx]=bf16(expm1(tbl)), n1=0 -
__global__ __launch_bounds__(256) void k_proj_qkv(
    const float* __restrict__ x, const float* __restrict__ Wq,
    const float* __restrict__ Wk, const float* __restrict__ Wv,
    const float* __restrict__ tbl, unsigned short* __restrict__ tblT,
    float* __restrict__ n1,
    float* __restrict__ QS, float* __restrict__ Ko, float* __restrict__ Vo)
{
    __shared__ __align__(16) float xs[64 * 128];
    __shared__ __align__(16) float Ws[32 * 128];
    const int t = threadIdx.x;
    const int m = blockIdx.z;            // 0..2 matrix select, 3 = prep
    if (m == 3) {
        const int bid2 = blockIdx.y * 108 + blockIdx.x;
        if (bid2 < 48) {
            const int idx = bid2 * 256 + t;
            if (idx < TABN) {
                float4 f0 = *reinterpret_cast<const float4*>(&tbl[idx * 8]);
                float4 f1 = *reinterpret_cast<const float4*>(&tbl[idx * 8 + 4]);
                tblT[0 * TSTRIDE + idx] = f2bf(expm1f(f0.x));
                tblT[1 * TSTRIDE + idx] = f2bf(expm1f(f0.y));
                tblT[2 * TSTRIDE + idx] = f2bf(expm1f(f0.z));
                tblT[3 * TSTRIDE + idx] = f2bf(expm1f(f0.w));
                tblT[4 * TSTRIDE + idx] = f2bf(expm1f(f1.x));
                tblT[5 * TSTRIDE + idx] = f2bf(expm1f(f1.y));
                tblT[6 * TSTRIDE + idx] = f2bf(expm1f(f1.z));
                tblT[7 * TSTRIDE + idx] = f2bf(expm1f(f1.w));
            }
        } else if (bid2 == 48) {
            ((float4*)n1)[t] = (float4){0.f, 0.f, 0.f, 0.f};
        }
        return;
    }
    const int row0 = blockIdx.x * 64;
    const int cg = blockIdx.y;           // 32-col group
    const float* __restrict__ W = (m == 0) ? Wq : (m == 1) ? Wk : Wv;

    {   // stage x tile, XOR-swizzled in 16B units
        const int cc = t & 31;
        #pragma unroll
        for (int p = 0; p < 8; ++p) {
            const int r = (t >> 5) + p * 8;
            float4 v = *reinterpret_cast<const float4*>(&x[(size_t)(row0 + r) * DIMC + cc * 4]);
            *reinterpret_cast<float4*>(&xs[r * 128 + ((cc * 4) ^ ((r & 7) << 2))]) = v;
        }
    }
    {   // stage W slice [32 cols][128 k]
        const int cc = t & 31;
        #pragma unroll
        for (int p = 0; p < 4; ++p) {
            const int c = (t >> 5) + p * 8;
            float4 v = *reinterpret_cast<const float4*>(&W[(size_t)(cg * 32 + c) * DIMC + cc * 4]);
            *reinterpret_cast<float4*>(&Ws[c * 128 + cc * 4]) = v;
        }
    }
    __syncthreads();
    const int nl = t & 63, w = t >> 6;
    float acc[8];
    #pragma unroll
    for (int c = 0; c < 8; ++c) acc[c] = 0.f;
    for (int k4 = 0; k4 < 32; ++k4) {
        const float4 xv = *reinterpret_cast<const float4*>(
            &xs[nl * 128 + ((k4 * 4) ^ ((nl & 7) << 2))]);
        #pragma unroll
        for (int c = 0; c < 8; ++c) {
            const float4 wv = *reinterpret_cast<const float4*>(&Ws[(w * 8 + c) * 128 + k4 * 4]);
            acc[c] = fmaf(xv.x, wv.x, fmaf(xv.y, wv.y,
                     fmaf(xv.z, wv.z, fmaf(xv.w, wv.w, acc[c]))));
        }
    }
    if (m == 0) {
        #pragma unroll
        for (int c = 0; c < 8; ++c) acc[c] = 1.f / (1.f + expf(-acc[c]));
    }
    __syncthreads();
    float* res = Ws;                      // reuse as 64x33 bounce buffer
    #pragma unroll
    for (int c = 0; c < 8; ++c) res[nl * 33 + w * 8 + c] = acc[c];
    __syncthreads();
    float* __restrict__ Out = (m == 0) ? QS : (m == 1) ? Ko : Vo;
    {
        const int r = t >> 2, q = t & 3;
        float4 v0, v1;
        v0.x = res[r*33 + q*8 + 0]; v0.y = res[r*33 + q*8 + 1];
        v0.z = res[r*33 + q*8 + 2]; v0.w = res[r*33 + q*8 + 3];
        v1.x = res[r*33 + q*8 + 4]; v1.y = res[r*33 + q*8 + 5];
        v1.z = res[r*33 + q*8 + 6]; v1.w = res[r*33 + q*8 + 7];
        *reinterpret_cast<float4*>(&Out[(size_t)(row0 + r) * DIMC + cg * 32 + q * 8]) = v0;
        *reinterpret_cast<float4*>(&Out[(size_t)(row0 + r) * DIMC + cg * 32 + q * 8 + 4]) = v1;
    }
}

// ---- K2: EKVt bf16 [h][b*32+c][j] + n1 partial colsums (atomicAdd) ---------
__global__ __launch_bounds__(256) void k_build_ekv(
    const float* __restrict__ Ko, const float* __restrict__ Vo,
    unsigned short* __restrict__ EKVt, float* __restrict__ n1)
{
    __shared__ float red[256][33];
    const int t = threadIdx.x;
    const int h = blockIdx.y;
    const int b = t >> 6, jj = t & 63;
    const int j = blockIdx.x * 64 + jj;
    const float* kp = &Ko[((size_t)b * NTOK + j) * DIMC + h * 16];
    const float* vp = &Vo[((size_t)b * NTOK + j) * DIMC + h * 16];
    float kv[16], vv[16], ob[32];
    #pragma unroll
    for (int d4 = 0; d4 < 4; ++d4) {
        *reinterpret_cast<float4*>(&kv[d4 * 4]) = *reinterpret_cast<const float4*>(&kp[d4 * 4]);
        *reinterpret_cast<float4*>(&vv[d4 * 4]) = *reinterpret_cast<const float4*>(&vp[d4 * 4]);
    }
    #pragma unroll
    for (int d = 0; d < 16; ++d) {
        float e = expf(kv[d]);            // kmax/bmax cancel in num/den
        ob[d] = e * vv[d];
        ob[16 + d] = e;
    }
    #pragma unroll
    for (int c = 0; c < 32; ++c)
        EKVt[((size_t)h * DIMC + b * 32 + c) * NTOK + j] = f2bf(ob[c]);
    #pragma unroll
    for (int c = 0; c < 32; ++c) red[t][c] = ob[c];
    __syncthreads();
    if (t < 128) {
        const int b2 = t >> 5, c = t & 31;
        float s = 0.f;
        for (int r = 0; r < 64; ++r) s += red[b2 * 64 + r][c];
        atomicAdd(&n1[(h * NB + b2) * 32 + c], s);
    }
}

// ---- K3: MFMA correction, LDS-staged table window --------------------------
// part[h][i][js][c] = sum_j w'_ij * ekv[j][c], w' = tblT[h][P(i)-P(j)+6083]
__global__ __launch_bounds__(256) void k_aft_mfma(
    const unsigned short* __restrict__ tblT,
    const unsigned short* __restrict__ EKVt,
    float* __restrict__ part)
{
    __shared__ __align__(16) unsigned short slds[2304];      // table window
    __shared__ __align__(16) unsigned short alds[64 * 64];   // w' tile, swizzled
    __shared__ __align__(16) unsigned short blds[128 * 64];  // ekv tile, swizzled
    const int t = threadIdx.x;
    const int i0 = blockIdx.x * 64;
    const int h = blockIdx.y;
    const int js = blockIdx.z;
    const int l = t & 63, w = t >> 6;
    const int il = l & 15, kg = l >> 4;

    // idx window: idx = P(i)+6083-P(j); P monotone; j-chunk is 4 aligned hi-blocks
    const int j_base = js * 576;
    const int pj_lo = js * 4 * 529;                 // P(j_base)
    const int pj_hi = pj_lo + 1851;                 // P(j_base + 575)
    const int idx_lo = Pdec(i0) + 6083 - pj_hi;     // >= 0
    {   // stage 2304 contiguous u16 (covers max window 2234)
        const unsigned short* src = &tblT[(size_t)h * TSTRIDE + idx_lo];
        #pragma unroll
        for (int p = 0; p < 9; ++p) slds[p * 256 + t] = src[p * 256 + t];
    }

    // per-wave row constants: qb[r] = P(i0 + w*16 + r) + 6083 - idx_lo
    const int gi0 = w * 16;
    int qb[16];
    #pragma unroll
    for (int r = 0; r < 16; ++r) qb[r] = Pdec(i0 + gi0 + r) + 6083 - idx_lo;

    const int bc = t >> 3;           // B-stage: c base
    const int bj8 = (t & 7) * 8;     // B-stage: j offset

    f32x4 acc[8];
    #pragma unroll
    for (int cf = 0; cf < 8; ++cf) acc[cf] = (f32x4){0.f, 0.f, 0.f, 0.f};

    for (int jt = 0; jt < 9; ++jt) {
        const int j0 = j_base + jt * 64;
        const int pj = Pdec(j0 + l);                // lane = j column
        __syncthreads();
        // stage B: EKVt[h][c][j0..j0+63] -> blds[c][j] (XOR-swizzled 16B units)
        #pragma unroll
        for (int p = 0; p < 4; ++p) {
            const int c = bc + p * 32;
            bf16x8 v = *reinterpret_cast<const bf16x8*>(
                &EKVt[((size_t)h * DIMC + c) * NTOK + j0 + bj8]);
            *reinterpret_cast<bf16x8*>(&blds[c * 64 + (bj8 ^ ((c & 7) << 3))]) = v;
        }
        // fill A from LDS table window (no global gather)
        #pragma unroll
        for (int r = 0; r < 16; ++r) {
            alds[(gi0 + r) * 64 + (l ^ ((r & 7) << 3))] = slds[qb[r] - pj];
        }
        __syncthreads();
        #pragma unroll
        for (int kk = 0; kk < 2; ++kk) {
            const int ia = w * 16 + il;
            const int ka = kk * 32 + kg * 8;
            bf16x8 af = *reinterpret_cast<const bf16x8*>(
                &alds[ia * 64 + (ka ^ ((ia & 7) << 3))]);
            #pragma unroll
            for (int cf = 0; cf < 8; ++cf) {
                const int cb = cf * 16 + il;
                bf16x8 bf = *reinterpret_cast<const bf16x8*>(
                    &blds[cb * 64 + (ka ^ ((cb & 7) << 3))]);
                acc[cf] = __builtin_amdgcn_mfma_f32_16x16x32_bf16(af, bf, acc[cf], 0, 0, 0);
            }
        }
    }
    #pragma unroll
    for (int cf = 0; cf < 8; ++cf) {
        #pragma unroll
        for (int r = 0; r < 4; ++r) {
            const int i = i0 + w * 16 + kg * 4 + r;   // D: row=(l>>4)*4+reg
            const int c = cf * 16 + il;               //    col=l&15
            part[(((size_t)h * NTOK + i) * 3 + js) * DIMC + c] = acc[cf][r];
        }
    }
}

// ---- K4: y = sigmoid(q) * (n1 + sum_js part_n) / (n1d + sum_js part_d) -----
// grid (8, 108): (h, 16-row chunk); thread: b = t&3, dq = (t>>2)&3, ri = t>>4
__global__ __launch_bounds__(256) void k_reduce_y(
    const float* __restrict__ part, const float* __restrict__ n1,
    const float* __restrict__ QS, float* __restrict__ Y)
{
    const int t = threadIdx.x;
    const int h = blockIdx.x;
    const int i = blockIdx.y * 16 + (t >> 4);
    const int b = t & 3, dq = (t >> 2) & 3;
    const float* pp = &part[((size_t)h * NTOK + i) * 3 * DIMC];
    float4 nu = *reinterpret_cast<const float4*>(&n1[(h * NB + b) * 32 + dq * 4]);
    float4 de = *reinterpret_cast<const float4*>(&n1[(h * NB + b) * 32 + 16 + dq * 4]);
    #pragma unroll
    for (int js = 0; js < 3; ++js) {
        float4 a  = *reinterpret_cast<const float4*>(&pp[js * DIMC + b * 32 + dq * 4]);
        float4 d4 = *reinterpret_cast<const float4*>(&pp[js * DIMC + b * 32 + 16 + dq * 4]);
        nu.x += a.x;  nu.y += a.y;  nu.z += a.z;  nu.w += a.w;
        de.x += d4.x; de.y += d4.y; de.z += d4.z; de.w += d4.w;
    }
    const size_t yb = ((size_t)b * NTOK + i) * DIMC + h * 16 + dq * 4;
    float4 q4 = *reinterpret_cast<const float4*>(&QS[yb]);
    float4 o;
    o.x = q4.x * nu.x / de.x;
    o.y = q4.y * nu.y / de.y;
    o.z = q4.z * nu.z / de.z;
    o.w = q4.w * nu.w / de.w;
    *reinterpret_cast<float4*>(&Y[yb]) = o;
}

// ---- K5: out = Y @ Wp^T + bp ----------------------------------------------
__global__ __launch_bounds__(256) void k_proj_out(
    const float* __restrict__ Y, const float* __restrict__ Wp,
    const float* __restrict__ bp, float* __restrict__ out)
{
    __shared__ __align__(16) float xs[64 * 128];
    __shared__ __align__(16) float Ws[32 * 128];
    const int t = threadIdx.x;
    const int row0 = blockIdx.x * 64;
    const int cg = blockIdx.y;
    {
        const int cc = t & 31;
        #pragma unroll
        for (int p = 0; p < 8; ++p) {
            const int r = (t >> 5) + p * 8;
            float4 v = *reinterpret_cast<const float4*>(&Y[(size_t)(row0 + r) * DIMC + cc * 4]);
            *reinterpret_cast<float4*>(&xs[r * 128 + ((cc * 4) ^ ((r & 7) << 2))]) = v;
        }
    }
    {
        const int cc = t & 31;
        #pragma unroll
        for (int p = 0; p < 4; ++p) {
            const int c = (t >> 5) + p * 8;
            float4 v = *reinterpret_cast<const float4*>(&Wp[(size_t)(cg * 32 + c) * DIMC + cc * 4]);
            *reinterpret_cast<float4*>(&Ws[c * 128 + cc * 4]) = v;
        }
    }
    __syncthreads();
    const int nl = t & 63, w = t >> 6;
    float acc[8];
    #pragma unroll
    for (int c = 0; c < 8; ++c) acc[c] = 0.f;
    for (int k4 = 0; k4 < 32; ++k4) {
        const float4 xv = *reinterpret_cast<const float4*>(
            &xs[nl * 128 + ((k4 * 4) ^ ((nl & 7) << 2))]);
        #pragma unroll
        for (int c = 0; c < 8; ++c) {
            const float4 wv = *reinterpret_cast<const float4*>(&Ws[(w * 8 + c) * 128 + k4 * 4]);
            acc[c] = fmaf(xv.x, wv.x, fmaf(xv.y, wv.y,
                     fmaf(xv.z, wv.z, fmaf(xv.w, wv.w, acc[c]))));
        }
    }
    #pragma unroll
    for (int c = 0; c < 8; ++c) acc[c] += bp[cg * 32 + w * 8 + c];
    __syncthreads();
    float* res = Ws;
    #pragma unroll
    for (int c = 0; c < 8; ++c) res[nl * 33 + w * 8 + c] = acc[c];
    __syncthreads();
    {
        const int r = t >> 2, q = t & 3;
        float4 v0, v1;
        v0.x = res[r*33 + q*8 + 0]; v0.y = res[r*33 + q*8 + 1];
        v0.z = res[r*33 + q*8 + 2]; v0.w = res[r*33 + q*8 + 3];
        v1.x = res[r*33 + q*8 + 4]; v1.y = res[r*33 + q*8 + 5];
        v1.z = res[r*33 + q*8 + 6]; v1.w = res[r*33 + q*8 + 7];
        *reinterpret_cast<float4*>(&out[(size_t)(row0 + r) * DIMC + cg * 32 + q * 8]) = v0;
        *reinterpret_cast<float4*>(&out[(size_t)(row0 + r) * DIMC + cg * 32 + q * 8 + 4]) = v1;
    }
}

extern "C" void kernel_launch(void* const* d_in, const int* in_sizes, int n_in,
                              void* d_out, int out_size, void* d_ws, size_t ws_size,
                              hipStream_t stream) {
    const float* x    = (const float*)d_in[0];
    const float* Wq   = (const float*)d_in[1];
    const float* Wk   = (const float*)d_in[2];
    const float* Wv   = (const float*)d_in[3];
    const float* Wp   = (const float*)d_in[4];
    const float* bp   = (const float*)d_in[5];
    const float* tbl  = (const float*)d_in[6];
    float* out = (float*)d_out;

    float* ws = (float*)d_ws;
    unsigned short* tblT = (unsigned short*)ws;     // 8*12168+2560 = 99904 u16 -> 49952 f32
    float* n1  = ws + 50000;                        // 1024 f32
    float* QS  = n1 + 1024;
    float* Ko  = QS + 884736;
    float* Vo  = Ko + 884736;
    unsigned short* EKVt = (unsigned short*)(Vo + 884736);   // 1769472 u16 = 884736 f32
    float* part = Vo + 884736 + 884736;             // 8*1728*3*128 = 5308416 f32
    float* Yb   = part + (size_t)NHEAD * NTOK * 3 * DIMC;    // 884736 f32

    k_proj_qkv<<<dim3(108, 4, 4), 256, 0, stream>>>(x, Wq, Wk, Wv, tbl, tblT, n1, QS, Ko, Vo);
    k_build_ekv<<<dim3(27, 8), 256, 0, stream>>>(Ko, Vo, EKVt, n1);
    k_aft_mfma<<<dim3(27, 8, 3), 256, 0, stream>>>(tblT, EKVt, part);
    k_reduce_y<<<dim3(8, 108), 256, 0, stream>>>(part, n1, QS, Yb);
    k_proj_out<<<dim3(108, 4), 256, 0, stream>>>(Yb, Wp, bp, out);
}